// Round 3
// baseline (1536.611 us; speedup 1.0000x reference)
//
#include <hip/hip_runtime.h>

#define E_    300
#define H2_   256
#define B_    64
#define S_    256
#define G_    (S_*B_)     // 16384
#define GATES (4*H2_)     // 1024
#define KREG  64          // weight cols per thread in VGPRs (16 float4)
#define WP4   49          // float4 pitch for wlds rows (192 data cols = 48 f4 + 1 pad)
#define HP    260         // float pitch for h rows (256 + 4 -> banks spread by 4*j)

// ---------------- prep: pack whh -> wpack[d][s][rr][k], bias sums ----------------
// wpack[((d*8+s)*128+rr)*256+k] = whh_d[r][k],  r=(rr>>5)*256 + s*32 + (rr&31)
__global__ void prep_kernel(const float* __restrict__ whh_f, const float* __restrict__ whh_b,
                            const float* __restrict__ bih_f, const float* __restrict__ bhh_f,
                            const float* __restrict__ bih_b, const float* __restrict__ bhh_b,
                            float* __restrict__ wpack, float* __restrict__ bsum) {
    int idx = blockIdx.x * blockDim.x + threadIdx.x;
    if (idx < 2 * 8 * 128 * 256) {             // 524288
        int d  = idx >> 18;
        int s  = (idx >> 15) & 7;
        int rr = (idx >> 8) & 127;
        int k  = idx & 255;
        int r  = ((rr >> 5) << 8) + s * 32 + (rr & 31);
        const float* w = d ? whh_b : whh_f;    // (1024, 256) row-major
        wpack[idx] = w[r * H2_ + k];
    }
    if (idx < 2 * GATES) {
        int d = idx >> 10, j = idx & 1023;
        bsum[idx] = d ? (bih_b[j] + bhh_b[j]) : (bih_f[j] + bhh_f[j]);
    }
}

// ---------------- input projection GEMM (unchanged) ----------------
__global__ __launch_bounds__(256) void xproj_kernel(
    const int* __restrict__ sent, const float* __restrict__ emb,
    const float* __restrict__ wih_f, const float* __restrict__ wih_b,
    const float* __restrict__ bsum, float* __restrict__ xp) {
    __shared__ float As[128 * 21];
    __shared__ float Bs[20 * 64];
    __shared__ int   toks[128];
    int gt = blockIdx.x, jt = blockIdx.y, d = blockIdx.z;
    const float* wih = d ? wih_b : wih_f;       // (1024, 300)
    int tid = threadIdx.x;
    int g0 = gt * 128, j0 = jt * 64;
    if (tid < 128) toks[tid] = sent[g0 + tid];
    __syncthreads();

    int ty = tid >> 4, tx = tid & 15;
    float acc[8][4];
    float4 bv = *(const float4*)&bsum[d * 1024 + j0 + tx * 4];
    #pragma unroll
    for (int i = 0; i < 8; i++) { acc[i][0] = bv.x; acc[i][1] = bv.y; acc[i][2] = bv.z; acc[i][3] = bv.w; }

    for (int kt = 0; kt < 15; kt++) {
        int k0 = kt * 20;
        #pragma unroll
        for (int l = 0; l < 10; l++) {
            int e = l * 256 + tid; int i = e / 20, k = e % 20;
            As[i * 21 + k] = emb[(long)toks[i] * E_ + k0 + k];
        }
        #pragma unroll
        for (int l = 0; l < 5; l++) {
            int e = l * 256 + tid; int k = e >> 6, j = e & 63;
            Bs[k * 64 + j] = wih[(j0 + j) * E_ + k0 + k];
        }
        __syncthreads();
        #pragma unroll
        for (int k = 0; k < 20; k++) {
            float4 b4 = *(const float4*)&Bs[k * 64 + tx * 4];
            #pragma unroll
            for (int i = 0; i < 8; i++) {
                float a = As[(ty * 8 + i) * 21 + k];
                acc[i][0] += a * b4.x; acc[i][1] += a * b4.y;
                acc[i][2] += a * b4.z; acc[i][3] += a * b4.w;
            }
        }
        __syncthreads();
    }
    #pragma unroll
    for (int i = 0; i < 8; i++) {
        float4 o; o.x = acc[i][0]; o.y = acc[i][1]; o.z = acc[i][2]; o.w = acc[i][3];
        *(float4*)&xp[((long)d * G_ + g0 + ty * 8 + i) * 1024 + j0 + tx * 4] = o;
    }
}

// ---------------- LSTM: 256 blocks = 32 groups (dir x 4-batch) x 8 unit-slices ----------------
// Block (G,s): 512 thr = 128 gate rows x 4 batches. 64 w-cols in VGPR, 192 in LDS.
// 8 slice-blocks of a group exchange 32x4 h-values/step via tagged u64 mailboxes.
__global__ __launch_bounds__(512, 2) void lstm_kernel(
    const float* __restrict__ xp, const float* __restrict__ wpack,
    const float* __restrict__ h0, const float* __restrict__ c0,
    float* __restrict__ hcat, unsigned long long* __restrict__ mbox) {
    __shared__ float4 wlds[128 * WP4];   // 100,352 B
    __shared__ float  h_lds[4 * HP];     //   4,160 B
    __shared__ float  g_stage[512];      //   2,048 B

    int t = threadIdx.x;
    int bid = blockIdx.x;
    int x = bid & 7, rest = bid >> 3;
    int s = rest & 7, Ghi = rest >> 3;
    int G = Ghi * 8 + x;                 // group 0..31; all slices of G share bid&7 (XCD)
    int d = G >> 4, bg = G & 15;
    int j = t & 3, rr = t >> 2;          // batch-in-group, local gate row
    int q = rr >> 5, uu = rr & 31;
    int r = q * 256 + s * 32 + uu;       // global gate row 0..1023
    int b = bg * 4 + j;

    const float* wp = wpack + (size_t)((d * 8 + s) * 128) * 256;

    // 64 cols -> VGPRs (small array, no spill risk)
    float4 wr[16];
    #pragma unroll
    for (int kk = 0; kk < 16; kk++) wr[kk] = ((const float4*)(wp + rr * 256))[kk];

    // 192 cols -> LDS, pitch 49 f4 (2-way bank aliasing only)
    for (int e = t; e < 128 * 48; e += 512) {
        int rrow = e / 48, kk = e % 48;
        wlds[rrow * WP4 + kk] = ((const float4*)(wp + rrow * 256 + KREG))[kk];
    }
    // h0 for the group's 4 batches
    for (int e = t; e < 1024; e += 512) {
        int jj = e >> 8, u = e & 255;
        h_lds[jj * HP + u] = h0[(d * B_ + bg * 4 + jj) * H2_ + u];
    }
    float c = 0.f;
    if (t < 128) c = c0[(d * B_ + b) * H2_ + s * 32 + uu];

    unsigned long long* mb_out = mbox + (size_t)(G * 8 + s) * 256;
    const float* xq = xp + (size_t)d * G_ * 1024 + r;
    float xcur;
    {
        int s0 = d ? 255 : 0;
        xcur = xq[(size_t)(s0 * 64 + b) * 1024];
    }
    __syncthreads();

    for (int step = 0; step < S_; step++) {
        // prefetch next step's x
        float xnext = 0.f;
        int sn = d ? (254 - step) : (step + 1);
        if (step < 255) xnext = xq[(size_t)(sn * 64 + b) * 1024];

        const float4* hj = (const float4*)&h_lds[j * HP];
        float a0 = xcur, a1 = 0.f, a2 = 0.f, a3 = 0.f;
        #pragma unroll
        for (int kk = 0; kk < 16; kk++) {
            float4 hv = hj[kk];
            a0 += wr[kk].x * hv.x; a1 += wr[kk].y * hv.y;
            a2 += wr[kk].z * hv.z; a3 += wr[kk].w * hv.w;
        }
        const float4* wrow = &wlds[rr * WP4];
        #pragma unroll
        for (int kk = 0; kk < 48; kk++) {
            float4 wv = wrow[kk]; float4 hv = hj[16 + kk];
            a0 += wv.x * hv.x; a1 += wv.y * hv.y;
            a2 += wv.z * hv.z; a3 += wv.w * hv.w;
        }
        g_stage[t] = (a0 + a1) + (a2 + a3);
        __syncthreads();

        int sidx = d ? (255 - step) : step;
        if (t < 128) {
            float iv = g_stage[t],        fv = g_stage[128 + t];
            float gv = g_stage[256 + t],  ov = g_stage[384 + t];
            float si = 1.f / (1.f + __expf(-iv));
            float sf = 1.f / (1.f + __expf(-fv));
            float so = 1.f / (1.f + __expf(-ov));
            float tg = tanhf(gv);
            c = sf * c + si * tg;
            float h = so * tanhf(c);
            h_lds[j * HP + s * 32 + uu] = h;
            union { float f; unsigned u; } cv; cv.f = h;
            __hip_atomic_store(&mb_out[(step & 1) * 128 + t],
                               ((unsigned long long)(unsigned)(step + 1) << 32) | cv.u,
                               __ATOMIC_RELAXED, __HIP_MEMORY_SCOPE_AGENT);
            hcat[(size_t)(sidx * 64 + b) * 512 + d * 256 + s * 32 + uu] = h;
        } else {
            int v = t - 128;                      // 384 pollers, 896 peer values
            #pragma unroll
            for (int it = 0; it < 3; it++) {
                int vv = v + it * 384;
                if (vv < 896) {
                    int spr = vv >> 7;
                    int sp = spr + (spr >= s ? 1 : 0);   // peer slice
                    int w = vv & 127;
                    unsigned long long* ad =
                        mbox + (size_t)(G * 8 + sp) * 256 + (step & 1) * 128 + w;
                    unsigned long long val;
                    do {
                        val = __hip_atomic_load(ad, __ATOMIC_RELAXED, __HIP_MEMORY_SCOPE_AGENT);
                    } while ((unsigned)(val >> 32) != (unsigned)(step + 1));
                    union { unsigned u; float f; } cv; cv.u = (unsigned)val;
                    h_lds[(w & 3) * HP + sp * 32 + (w >> 2)] = cv.f;
                }
            }
        }
        __syncthreads();
        xcur = xnext;
    }
}

// ---------------- feats (unchanged) ----------------
__global__ void feats_kernel(const float* __restrict__ hcat, const float* __restrict__ Wout,
                             const float* __restrict__ bout, float* __restrict__ feats) {
    int tid = threadIdx.x; int w = tid >> 6, l = tid & 63;
    int g = blockIdx.x * 4 + w;
    float r[8];
    #pragma unroll
    for (int m = 0; m < 8; m++) r[m] = hcat[(long)g * 512 + m * 64 + l];
    #pragma unroll
    for (int tt = 0; tt < 10; tt++) {
        float a = 0.f;
        #pragma unroll
        for (int m = 0; m < 8; m++) a += r[m] * Wout[tt * 512 + m * 64 + l];
        #pragma unroll
        for (int off = 32; off > 0; off >>= 1) a += __shfl_down(a, off);
        if (l == 0) feats[g * 10 + tt] = a + bout[tt];
    }
}

// ---------------- Viterbi (unchanged) ----------------
__global__ void viterbi_kernel(const float* __restrict__ feats, const float* __restrict__ trans,
                               float* __restrict__ out) {
    __shared__ unsigned char bp[256 * 16];
    int l = threadIdx.x; int b = blockIdx.x;
    float trrow[10];
    #pragma unroll
    for (int p = 0; p < 10; p++) trrow[p] = (l < 10) ? trans[l * 10 + p] : 0.f;
    float tr_stop = (l < 10) ? trans[90 + l] : -3e38f;
    float fv = (l == 8) ? 0.f : -10000.f;

    for (int s = 0; s < 256; s++) {
        float m = -3e38f; int arg = 0;
        #pragma unroll
        for (int p = 0; p < 10; p++) {
            float v = __shfl(fv, p) + trrow[p];
            if (v > m) { m = v; arg = p; }
        }
        float ft = (l < 10) ? feats[((long)b * 256 + s) * 10 + l] : 0.f;
        fv = m + ft;
        if (l < 10) bp[s * 16 + l] = (unsigned char)arg;
    }
    __syncthreads();
    float term = fv + tr_stop;
    float best = -3e38f; int bt = 0;
    #pragma unroll
    for (int p = 0; p < 10; p++) {
        float v = __shfl(term, p);
        if (v > best) { best = v; bt = p; }
    }
    if (l == 0) {
        out[b] = best;
        int cur = bt;
        out[64 + b * 256 + 255] = (float)cur;
        for (int s = 254; s >= 0; s--) {
            cur = bp[(s + 1) * 16 + cur];
            out[64 + b * 256 + s] = (float)cur;
        }
    }
}

extern "C" void kernel_launch(void* const* d_in, const int* in_sizes, int n_in,
                              void* d_out, int out_size, void* d_ws, size_t ws_size,
                              hipStream_t stream) {
    const int*   sent  = (const int*)  d_in[0];
    const float* emb   = (const float*)d_in[1];
    const float* wih_f = (const float*)d_in[2];
    const float* whh_f = (const float*)d_in[3];
    const float* bih_f = (const float*)d_in[4];
    const float* bhh_f = (const float*)d_in[5];
    const float* wih_b = (const float*)d_in[6];
    const float* whh_b = (const float*)d_in[7];
    const float* bih_b = (const float*)d_in[8];
    const float* bhh_b = (const float*)d_in[9];
    const float* Wout  = (const float*)d_in[10];
    const float* bout  = (const float*)d_in[11];
    const float* h0    = (const float*)d_in[12];
    const float* c0    = (const float*)d_in[13];
    const float* trans = (const float*)d_in[14];

    float* ws    = (float*)d_ws;
    float* xp    = ws;                  // [2][16384][1024] = 33,554,432 f
    float* hcat  = ws + 33554432;       // [16384][512]     =  8,388,608 f
    float* wpack = ws + 41943040;       // [2][8][128][256] =    524,288 f
    float* bsum  = ws + 42467328;       // [2][1024]        =      2,048 f
    unsigned long long* mbox = (unsigned long long*)(ws + 42469376); // 65,536 u64 = 512 KB
    float* feats = ws;                  // aliases xp (dead after lstm)
    float* out   = (float*)d_out;

    hipLaunchKernelGGL(prep_kernel, dim3(2048), dim3(256), 0, stream,
                       whh_f, whh_b, bih_f, bhh_f, bih_b, bhh_b, wpack, bsum);
    hipLaunchKernelGGL(xproj_kernel, dim3(128, 16, 2), dim3(256), 0, stream,
                       sent, emb, wih_f, wih_b, bsum, xp);

    void* lstm_args[] = { (void*)&xp, (void*)&wpack, (void*)&h0, (void*)&c0,
                          (void*)&hcat, (void*)&mbox };
    hipLaunchCooperativeKernel((const void*)lstm_kernel, dim3(256), dim3(512),
                               lstm_args, 0, stream);

    hipLaunchKernelGGL(feats_kernel, dim3(4096), dim3(256), 0, stream,
                       hcat, Wout, bout, feats);
    hipLaunchKernelGGL(viterbi_kernel, dim3(64), dim3(64), 0, stream,
                       feats, trans, out);
}

// Round 4
// 1454.426 us; speedup vs baseline: 1.0565x; 1.0565x over previous
//
#include <hip/hip_runtime.h>

#define E_    300
#define H2_   256
#define B_    64
#define S_    256
#define G_    (S_*B_)     // 16384
#define GATES (4*H2_)     // 1024
#define NS    8           // unit slices per direction

// ---------------- prep: pack whh for per-thread f4 runs + bias sums ----------------
// wpack[((d*8+s)*512 + t)*64 + gt*16 + kk] = whh_d[gt*256 + s*32 + (t>>4)][ (t&15)*16 + kk ]
__global__ void prep_kernel(const float* __restrict__ whh_f, const float* __restrict__ whh_b,
                            const float* __restrict__ bih_f, const float* __restrict__ bhh_f,
                            const float* __restrict__ bih_b, const float* __restrict__ bhh_b,
                            float* __restrict__ wpack, float* __restrict__ bsum) {
    int idx = blockIdx.x * blockDim.x + threadIdx.x;
    if (idx < 2 * 8 * 512 * 64) {              // 524288
        int d  = idx >> 18;
        int s  = (idx >> 15) & 7;
        int t  = (idx >> 6) & 511;
        int e  = idx & 63;
        int gt = e >> 4, kk = e & 15;
        int u  = t >> 4, cc = t & 15;
        int row = gt * 256 + s * 32 + u;
        int col = cc * 16 + kk;
        const float* w = d ? whh_b : whh_f;    // (1024, 256) row-major
        wpack[idx] = w[row * H2_ + col];
    }
    if (idx < 2 * GATES) {
        int d = idx >> 10, j = idx & 1023;
        bsum[idx] = d ? (bih_b[j] + bhh_b[j]) : (bih_f[j] + bhh_f[j]);
    }
}

// ---------------- input projection GEMM (unchanged) ----------------
__global__ __launch_bounds__(256) void xproj_kernel(
    const int* __restrict__ sent, const float* __restrict__ emb,
    const float* __restrict__ wih_f, const float* __restrict__ wih_b,
    const float* __restrict__ bsum, float* __restrict__ xp) {
    __shared__ float As[128 * 21];
    __shared__ float Bs[20 * 64];
    __shared__ int   toks[128];
    int gt = blockIdx.x, jt = blockIdx.y, d = blockIdx.z;
    const float* wih = d ? wih_b : wih_f;       // (1024, 300)
    int tid = threadIdx.x;
    int g0 = gt * 128, j0 = jt * 64;
    if (tid < 128) toks[tid] = sent[g0 + tid];
    __syncthreads();

    int ty = tid >> 4, tx = tid & 15;
    float acc[8][4];
    float4 bv = *(const float4*)&bsum[d * 1024 + j0 + tx * 4];
    #pragma unroll
    for (int i = 0; i < 8; i++) { acc[i][0] = bv.x; acc[i][1] = bv.y; acc[i][2] = bv.z; acc[i][3] = bv.w; }

    for (int kt = 0; kt < 15; kt++) {
        int k0 = kt * 20;
        #pragma unroll
        for (int l = 0; l < 10; l++) {
            int e = l * 256 + tid; int i = e / 20, k = e % 20;
            As[i * 21 + k] = emb[(long)toks[i] * E_ + k0 + k];
        }
        #pragma unroll
        for (int l = 0; l < 5; l++) {
            int e = l * 256 + tid; int k = e >> 6, j = e & 63;
            Bs[k * 64 + j] = wih[(j0 + j) * E_ + k0 + k];
        }
        __syncthreads();
        #pragma unroll
        for (int k = 0; k < 20; k++) {
            float4 b4 = *(const float4*)&Bs[k * 64 + tx * 4];
            #pragma unroll
            for (int i = 0; i < 8; i++) {
                float a = As[(ty * 8 + i) * 21 + k];
                acc[i][0] += a * b4.x; acc[i][1] += a * b4.y;
                acc[i][2] += a * b4.z; acc[i][3] += a * b4.w;
            }
        }
        __syncthreads();
    }
    #pragma unroll
    for (int i = 0; i < 8; i++) {
        float4 o; o.x = acc[i][0]; o.y = acc[i][1]; o.z = acc[i][2]; o.w = acc[i][3];
        *(float4*)&xp[((long)d * G_ + g0 + ty * 8 + i) * 1024 + j0 + tx * 4] = o;
    }
}

// ---------------- LSTM: 256 blocks = 32 groups (dir x 4-batch) x 8 unit-slices ----------------
// Register-blocked GEMV: thread (u,cc) computes 4 gate rows x 16 k x 4 batches,
// weights fully VGPR-resident (16 f4). cc-reduction via padded LDS + 4-lane shfl.
__global__ __launch_bounds__(512, 2) void lstm_kernel(
    const float* __restrict__ xp, const float* __restrict__ wpack,
    const float* __restrict__ h0, const float* __restrict__ c0,
    float* __restrict__ hcat, unsigned long long* __restrict__ mbox) {
    __shared__ float h_cur[4 * 320];   // [j][kb 16][20-pad]  (5 KB)
    __shared__ float part[4 * 2180];   // [gt]{2180}[u]{68}[cc]{4}  (~35 KB)

    int t = threadIdx.x;
    int bid = blockIdx.x;
    int x = bid & 7, rest = bid >> 3;
    int s = rest & 7, Ghi = rest >> 3;
    int G = Ghi * 8 + x;               // slices of G share bid&7 (XCD colocation)
    int d = G >> 4, bg = G & 15;

    // weights -> VGPRs (16 f4 per thread, proven spill-free size)
    float4 w[4][4];
    const float4* wbase = (const float4*)(wpack + (size_t)((d * 8 + s) * 512 + t) * 64);
    #pragma unroll
    for (int gt = 0; gt < 4; gt++)
        #pragma unroll
        for (int k4 = 0; k4 < 4; k4++)
            w[gt][k4] = wbase[gt * 4 + k4];

    int fu = t >> 4, fcc = t & 15;     // FMA role
    int rgt = t & 3, ru = t >> 2;      // reduction role (t<128)

    for (int e = t; e < 1024; e += 512) {
        int j = e >> 8, k = e & 255;
        h_cur[j * 320 + (k >> 4) * 20 + (k & 15)] = h0[(d * B_ + bg * 4 + j) * H2_ + k];
    }
    float c[4] = {0.f, 0.f, 0.f, 0.f};
    if (t < 128 && rgt == 0) {
        #pragma unroll
        for (int j = 0; j < 4; j++)
            c[j] = c0[(d * B_ + bg * 4 + j) * H2_ + s * 32 + ru];
    }
    unsigned long long* mb_out = mbox + (size_t)(G * NS + s) * 256;
    const size_t xbase = (size_t)d * G_ * 1024;
    __syncthreads();

    for (int step = 0; step < S_; step++) {
        int sidx = d ? (255 - step) : step;
        float xv[4] = {0.f, 0.f, 0.f, 0.f};
        if (t < 128) {                  // xp for this thread's (gt,u) row, 4 batches
            #pragma unroll
            for (int j = 0; j < 4; j++)
                xv[j] = xp[xbase + (size_t)(sidx * 64 + bg * 4 + j) * 1024
                           + rgt * 256 + s * 32 + ru];
        }
        // ---- register-blocked partial GEMV ----
        float acc[4][4];
        #pragma unroll
        for (int gt = 0; gt < 4; gt++)
            #pragma unroll
            for (int j = 0; j < 4; j++) acc[gt][j] = 0.f;
        #pragma unroll
        for (int j = 0; j < 4; j++) {
            const float* hb = &h_cur[j * 320 + fcc * 20];
            #pragma unroll
            for (int k4 = 0; k4 < 4; k4++) {
                float4 h4 = *(const float4*)(hb + k4 * 4);
                #pragma unroll
                for (int gt = 0; gt < 4; gt++) {
                    acc[gt][j] += w[gt][k4].x * h4.x + w[gt][k4].y * h4.y
                                + w[gt][k4].z * h4.z + w[gt][k4].w * h4.w;
                }
            }
        }
        #pragma unroll
        for (int gt = 0; gt < 4; gt++) {
            float4 p; p.x = acc[gt][0]; p.y = acc[gt][1]; p.z = acc[gt][2]; p.w = acc[gt][3];
            *(float4*)&part[gt * 2180 + fu * 68 + fcc * 4] = p;
        }
        __syncthreads();

        if (t < 128) {
            // ---- 16-way cc reduction + xp ----
            float4 sum; sum.x = xv[0]; sum.y = xv[1]; sum.z = xv[2]; sum.w = xv[3];
            #pragma unroll
            for (int cc = 0; cc < 16; cc++) {
                float4 p = *(const float4*)&part[rgt * 2180 + ru * 68 + cc * 4];
                sum.x += p.x; sum.y += p.y; sum.z += p.z; sum.w += p.w;
            }
            // gather 4 gate types within each 4-lane group (no barrier)
            int lb = t & ~3;
            float gi[4], gf[4], gg[4], go[4];
            #pragma unroll
            for (int j = 0; j < 4; j++) {
                float v = (&sum.x)[j];
                gi[j] = __shfl(v, lb + 0);
                gf[j] = __shfl(v, lb + 1);
                gg[j] = __shfl(v, lb + 2);
                go[j] = __shfl(v, lb + 3);
            }
            if (rgt == 0) {
                int u = ru, k = s * 32 + u;
                #pragma unroll
                for (int j = 0; j < 4; j++) {
                    float si = 1.f / (1.f + __expf(-gi[j]));
                    float sf = 1.f / (1.f + __expf(-gf[j]));
                    float so = 1.f / (1.f + __expf(-go[j]));
                    float tg = tanhf(gg[j]);
                    c[j] = sf * c[j] + si * tg;
                    float h = so * tanhf(c[j]);
                    h_cur[j * 320 + (k >> 4) * 20 + (k & 15)] = h;
                    union { float f; unsigned u32; } cv; cv.f = h;
                    __hip_atomic_store(&mb_out[(step & 1) * 128 + j * 32 + u],
                        ((unsigned long long)(unsigned)(step + 1) << 32) | cv.u32,
                        __ATOMIC_RELAXED, __HIP_MEMORY_SCOPE_AGENT);
                    hcat[(size_t)(sidx * 64 + bg * 4 + j) * 512 + d * 256 + k] = h;
                }
            }
        } else {
            // ---- ingest 7 peer slices (896 values over 384 pollers) ----
            int pt = t - 128;
            #pragma unroll
            for (int r = 0; r < 3; r++) {
                int vv = pt + r * 384;
                if (vv < 896) {
                    int spr = vv >> 7;
                    int sp = spr + (spr >= s ? 1 : 0);
                    int rem = vv & 127;
                    int j = rem >> 5, u = rem & 31;
                    unsigned long long* ad =
                        mbox + (size_t)(G * NS + sp) * 256 + (step & 1) * 128 + rem;
                    unsigned long long val;
                    do {
                        val = __hip_atomic_load(ad, __ATOMIC_RELAXED, __HIP_MEMORY_SCOPE_AGENT);
                    } while ((unsigned)(val >> 32) != (unsigned)(step + 1));
                    union { unsigned u32; float f; } cv; cv.u32 = (unsigned)val;
                    int k = sp * 32 + u;
                    h_cur[j * 320 + (k >> 4) * 20 + (k & 15)] = cv.f;
                }
            }
        }
        __syncthreads();
    }
}

// ---------------- feats (unchanged) ----------------
__global__ void feats_kernel(const float* __restrict__ hcat, const float* __restrict__ Wout,
                             const float* __restrict__ bout, float* __restrict__ feats) {
    int tid = threadIdx.x; int w = tid >> 6, l = tid & 63;
    int g = blockIdx.x * 4 + w;
    float r[8];
    #pragma unroll
    for (int m = 0; m < 8; m++) r[m] = hcat[(long)g * 512 + m * 64 + l];
    #pragma unroll
    for (int tt = 0; tt < 10; tt++) {
        float a = 0.f;
        #pragma unroll
        for (int m = 0; m < 8; m++) a += r[m] * Wout[tt * 512 + m * 64 + l];
        #pragma unroll
        for (int off = 32; off > 0; off >>= 1) a += __shfl_down(a, off);
        if (l == 0) feats[g * 10 + tt] = a + bout[tt];
    }
}

// ---------------- Viterbi (unchanged) ----------------
__global__ void viterbi_kernel(const float* __restrict__ feats, const float* __restrict__ trans,
                               float* __restrict__ out) {
    __shared__ unsigned char bp[256 * 16];
    int l = threadIdx.x; int b = blockIdx.x;
    float trrow[10];
    #pragma unroll
    for (int p = 0; p < 10; p++) trrow[p] = (l < 10) ? trans[l * 10 + p] : 0.f;
    float tr_stop = (l < 10) ? trans[90 + l] : -3e38f;
    float fv = (l == 8) ? 0.f : -10000.f;

    for (int s = 0; s < 256; s++) {
        float m = -3e38f; int arg = 0;
        #pragma unroll
        for (int p = 0; p < 10; p++) {
            float v = __shfl(fv, p) + trrow[p];
            if (v > m) { m = v; arg = p; }
        }
        float ft = (l < 10) ? feats[((long)b * 256 + s) * 10 + l] : 0.f;
        fv = m + ft;
        if (l < 10) bp[s * 16 + l] = (unsigned char)arg;
    }
    __syncthreads();
    float term = fv + tr_stop;
    float best = -3e38f; int bt = 0;
    #pragma unroll
    for (int p = 0; p < 10; p++) {
        float v = __shfl(term, p);
        if (v > best) { best = v; bt = p; }
    }
    if (l == 0) {
        out[b] = best;
        int cur = bt;
        out[64 + b * 256 + 255] = (float)cur;
        for (int s = 254; s >= 0; s--) {
            cur = bp[(s + 1) * 16 + cur];
            out[64 + b * 256 + s] = (float)cur;
        }
    }
}

extern "C" void kernel_launch(void* const* d_in, const int* in_sizes, int n_in,
                              void* d_out, int out_size, void* d_ws, size_t ws_size,
                              hipStream_t stream) {
    const int*   sent  = (const int*)  d_in[0];
    const float* emb   = (const float*)d_in[1];
    const float* wih_f = (const float*)d_in[2];
    const float* whh_f = (const float*)d_in[3];
    const float* bih_f = (const float*)d_in[4];
    const float* bhh_f = (const float*)d_in[5];
    const float* wih_b = (const float*)d_in[6];
    const float* whh_b = (const float*)d_in[7];
    const float* bih_b = (const float*)d_in[8];
    const float* bhh_b = (const float*)d_in[9];
    const float* Wout  = (const float*)d_in[10];
    const float* bout  = (const float*)d_in[11];
    const float* h0    = (const float*)d_in[12];
    const float* c0    = (const float*)d_in[13];
    const float* trans = (const float*)d_in[14];

    float* ws    = (float*)d_ws;
    float* xp    = ws;                  // [2][16384][1024] = 33,554,432 f
    float* hcat  = ws + 33554432;       // [16384][512]     =  8,388,608 f
    float* wpack = ws + 41943040;       // [2][8][512][64]  =    524,288 f
    float* bsum  = ws + 42467328;       // [2][1024]        =      2,048 f
    unsigned long long* mbox = (unsigned long long*)(ws + 42469376); // 65,536 u64
    float* feats = ws;                  // aliases xp (dead after lstm)
    float* out   = (float*)d_out;

    hipLaunchKernelGGL(prep_kernel, dim3(2048), dim3(256), 0, stream,
                       whh_f, whh_b, bih_f, bhh_f, bih_b, bhh_b, wpack, bsum);
    hipLaunchKernelGGL(xproj_kernel, dim3(128, 16, 2), dim3(256), 0, stream,
                       sent, emb, wih_f, wih_b, bsum, xp);

    void* lstm_args[] = { (void*)&xp, (void*)&wpack, (void*)&h0, (void*)&c0,
                          (void*)&hcat, (void*)&mbox };
    hipLaunchCooperativeKernel((const void*)lstm_kernel, dim3(256), dim3(512),
                               lstm_args, 0, stream);

    hipLaunchKernelGGL(feats_kernel, dim3(4096), dim3(256), 0, stream,
                       hcat, Wout, bout, feats);
    hipLaunchKernelGGL(viterbi_kernel, dim3(64), dim3(64), 0, stream,
                       feats, trans, out);
}